// Round 4
// baseline (494.835 us; speedup 1.0000x reference)
//
#include <hip/hip_runtime.h>
#include <hip/hip_bf16.h>
#include <stdint.h>

// ---------------------------------------------------------------------------
// UpdateSpeaker: GRU-like gating block.
//   r,p,z = sigmoid(X@Wx*^T + S@Wh*^T + A@Vh*^T)
//   h~    = tanh(X@Wxh^T + (r*S)@Whh^T + (p*A)@Vhh^T)
//   out   = (1-z)*S + z*h~
// GEMM1: 256x256 8-phase + read skew; fragment reads are INLINE-ASM
//        ds_read_b128 so the compiler's waitcnt pass cannot insert
//        conservative vmcnt(0) drains before them (LDS-DMA alias guard).
// GEMM2: m97 128x128 structure.
// ---------------------------------------------------------------------------

typedef short  short8  __attribute__((ext_vector_type(8)));
typedef unsigned short ushort8 __attribute__((ext_vector_type(8)));
typedef float  f32x4   __attribute__((ext_vector_type(4)));

static constexpr int Bn  = 16384;  // batch

__device__ __forceinline__ unsigned short f2bf(float x) {
  union { float f; unsigned u; } v; v.f = x;
  unsigned r = v.u + 0x7fffu + ((v.u >> 16) & 1u);   // RNE
  return (unsigned short)(r >> 16);
}
__device__ __forceinline__ float bf2f(unsigned short h) {
  union { unsigned u; float f; } v; v.u = ((unsigned)h) << 16; return v.f;
}
__device__ __forceinline__ float sigm(float x) { return 1.0f / (1.0f + __expf(-x)); }
__device__ __forceinline__ float tanh_fast(float x) {
  return 2.0f / (1.0f + __expf(-2.0f * x)) - 1.0f;
}

__device__ __forceinline__ void gload_lds16(const void* g, void* l) {
  __builtin_amdgcn_global_load_lds((const __attribute__((address_space(1))) void*)g,
                                   (__attribute__((address_space(3))) void*)l,
                                   16, 0, 0);
}

// raw LDS read, invisible to the compiler's waitcnt-insertion pass
__device__ __forceinline__ short8 lds_read_b128(unsigned off) {
  short8 r;
  asm volatile("ds_read_b128 %0, %1" : "=v"(r) : "v"(off));
  return r;
}

// ---- weight packing -------------------------------------------------------
__global__ __launch_bounds__(256) void pack_w1(
    const float* __restrict__ xr, const float* __restrict__ xp,
    const float* __restrict__ xz, const float* __restrict__ xh,
    const float* __restrict__ hr, const float* __restrict__ hp, const float* __restrict__ hz,
    const float* __restrict__ vr, const float* __restrict__ vp, const float* __restrict__ vz,
    unsigned short* __restrict__ W1)
{
  int idx = blockIdx.x * 256 + threadIdx.x;
  int n  = idx >> 8;
  int k8 = (idx & 255) << 3;
  int g = n >> 9, j = n & 511;
  const float* src = nullptr;
  if (k8 < 1024) {
    const float* x = (g == 0) ? xr : (g == 1) ? xp : (g == 2) ? xz : xh;
    src = x + (size_t)j * 1024 + k8;
  } else if (k8 < 1536) {
    if (g < 3) { const float* h = (g == 0) ? hr : (g == 1) ? hp : hz; src = h + (size_t)j * 512 + (k8 - 1024); }
  } else {
    if (g < 3) { const float* v = (g == 0) ? vr : (g == 1) ? vp : vz; src = v + (size_t)j * 512 + (k8 - 1536); }
  }
  ushort8 o;
  if (src) { for (int i = 0; i < 8; i++) o[i] = f2bf(src[i]); }
  else     { for (int i = 0; i < 8; i++) o[i] = 0; }
  *(ushort8*)&W1[(size_t)n * 2048 + k8] = o;
}

__global__ __launch_bounds__(256) void pack_w2(
    const float* __restrict__ hh, const float* __restrict__ vh,
    unsigned short* __restrict__ W2)
{
  int idx = blockIdx.x * 256 + threadIdx.x;
  int n  = idx >> 7;
  int k8 = (idx & 127) << 3;
  const float* src = (k8 < 512) ? hh + (size_t)n * 512 + k8
                                : vh + (size_t)n * 512 + (k8 - 512);
  ushort8 o;
  for (int i = 0; i < 8; i++) o[i] = f2bf(src[i]);
  *(ushort8*)&W2[(size_t)n * 1024 + k8] = o;
}

__global__ __launch_bounds__(256) void pack_u(
    const float* __restrict__ X, const float* __restrict__ S, const float* __restrict__ A,
    unsigned short* __restrict__ U)
{
  int idx = blockIdx.x * 256 + threadIdx.x;
  int b  = idx >> 8;
  int c8 = (idx & 255) << 3;
  const float* src = (c8 < 1024) ? X + (size_t)b * 1024 + c8
                   : (c8 < 1536) ? S + (size_t)b * 512 + (c8 - 1024)
                                 : A + (size_t)b * 512 + (c8 - 1536);
  f32x4 lo = *(const f32x4*)src;
  f32x4 hi = *(const f32x4*)(src + 4);
  ushort8 o;
  o[0] = f2bf(lo[0]); o[1] = f2bf(lo[1]); o[2] = f2bf(lo[2]); o[3] = f2bf(lo[3]);
  o[4] = f2bf(hi[0]); o[5] = f2bf(hi[1]); o[6] = f2bf(hi[2]); o[7] = f2bf(hi[3]);
  *(ushort8*)&U[(size_t)b * 2048 + c8] = o;
}

// ---- GEMM1: 256x256 tile, BK=64, 8 waves (2Mx4N), 8-phase + read skew -----
__global__ __launch_bounds__(512, 1) void gemm256_epi1(
    const unsigned short* __restrict__ Amat,
    const unsigned short* __restrict__ Bmat,
    const int K,
    const float* __restrict__ Sv, const float* __restrict__ Av,
    unsigned short* __restrict__ U2, unsigned short* __restrict__ Zp,
    unsigned short* __restrict__ XHp)
{
  extern __shared__ char lds[];
  constexpr int B_OFF = 65536;

  const int tid  = threadIdx.x;
  const int lane = tid & 63, wave = tid >> 6;
  const int wm = wave >> 2, wn = wave & 3;      // 2 x 4 wave grid
  const int fr = lane & 15, fq = lane >> 4;
  const int m0 = blockIdx.y * 256, n0 = blockIdx.x * 256;

  // staging: thread covers (row = tid>>3 [+64], slot = tid&7) of a half-tile
  const int srow  = tid >> 3;
  const int sslot = (tid & 7) ^ (srow & 7);     // pre-swizzled source slot
  const unsigned short* gA = Amat + (size_t)(m0 + srow) * K + sslot * 8;
  const unsigned short* gB = Bmat + (size_t)(n0 + srow) * K + sslot * 8;
  const size_t K64 = (size_t)64 * K, K128 = (size_t)128 * K;

  // ds_read swizzle offsets (row&7 == fr&7 for all fragment rows)
  int swz[2];
  swz[0] = ((fq    ) ^ (fr & 7)) << 4;
  swz[1] = ((fq + 4) ^ (fr & 7)) << 4;

  // raw 32-bit LDS byte offsets for inline-asm ds_read
  const unsigned ldsBase =
      (unsigned)(unsigned long long)(__attribute__((address_space(3))) char*)lds;
  const unsigned obaseA = ldsBase + wm * 16384 + fr * 128;
  const unsigned obaseB = ldsBase + B_OFF + (wn >> 1) * 16384 + ((wn & 1) * 64 + fr) * 128;

  f32x4 acc[8][4] = {};
  short8 aA[2][2], aB[2][2], b[4][2];

  const int NT  = K >> 6;
  const int NIT = K >> 7;

  auto STAGE = [&](int mat, int half, int buf, int tile) {
    const unsigned short* g = (mat ? gB : gA) + (size_t)half * K128 + (tile << 6);
    char* l = lds + (mat ? B_OFF : 0) + buf * 32768 + half * 16384 + tid * 16;
    gload_lds16(g, l);
    gload_lds16(g + K64, l + 8192);
  };
  auto DSA2 = [&](int buf, int mc, short8 (&bank)[2][2]) {   // 4 ds_read_b128
#pragma unroll
    for (int i = 0; i < 2; i++) {
      const unsigned p = obaseA + buf * 32768 + (mc * 2 + i) * 2048;
#pragma unroll
      for (int ks = 0; ks < 2; ks++)
        bank[i][ks] = lds_read_b128(p + swz[ks]);
    }
  };
  auto DSB8 = [&](int buf) {                                 // 8 ds_read_b128
#pragma unroll
    for (int j = 0; j < 4; j++) {
      const unsigned p = obaseB + buf * 32768 + j * 2048;
#pragma unroll
      for (int ks = 0; ks < 2; ks++)
        b[j][ks] = lds_read_b128(p + swz[ks]);
    }
  };
  auto MMA = [&](int mc, short8 (&bank)[2][2]) {             // 16 MFMA
    __builtin_amdgcn_s_setprio(1);
#pragma unroll
    for (int i = 0; i < 2; i++)
#pragma unroll
      for (int j = 0; j < 4; j++)
#pragma unroll
        for (int ks = 0; ks < 2; ks++)
          acc[mc * 2 + i][j] = __builtin_amdgcn_mfma_f32_16x16x32_bf16(
              bank[i][ks], b[j][ks], acc[mc * 2 + i][j], 0, 0, 0);
    __builtin_amdgcn_s_setprio(0);
  };

#define PH_TAIL(MC, BANK)                                     \
  __builtin_amdgcn_s_barrier();                               \
  asm volatile("s_waitcnt lgkmcnt(4)" ::: "memory");          \
  __builtin_amdgcn_sched_barrier(0);                          \
  MMA(MC, BANK);                                              \
  __builtin_amdgcn_s_barrier();

  // ---- prologue: tile0 (A+B) -> buf0, B(tile1) -> buf1 ----
  STAGE(0, 0, 0, 0); STAGE(0, 1, 0, 0);
  STAGE(1, 0, 0, 0); STAGE(1, 1, 0, 0);
  STAGE(1, 0, 1, 1); STAGE(1, 1, 1, 1);
  asm volatile("s_waitcnt vmcnt(4)" ::: "memory");   // tile0 landed; B(t1) flying
  __builtin_amdgcn_s_barrier();
  DSA2(0, 0, aA);                                    // mc0 for ph1

  for (int I = 0; I < NIT; ++I) {
    const int t1 = 2 * I + 1;
    const int t2 = (2 * I + 2 < NT) ? 2 * I + 2 : NT - 1;
    const int t3 = (2 * I + 3 < NT) ? 2 * I + 3 : NT - 1;
    // ph1: b(buf0) + next-a(mc1); MMA mc0
    DSB8(0); DSA2(0, 1, aB); STAGE(0, 0, 1, t1);
    PH_TAIL(0, aA)
    // ph2
    DSA2(0, 2, aA); STAGE(0, 1, 1, t1);
    PH_TAIL(1, aB)
    // ph3
    DSA2(0, 3, aB); STAGE(1, 0, 0, t2);
    PH_TAIL(2, aA)
    // ph4: vmcnt + collective barrier BEFORE cross-buffer a-read
    STAGE(1, 1, 0, t2);
    asm volatile("s_waitcnt vmcnt(4)" ::: "memory");  // buf1 (tile t1) landed
    __builtin_amdgcn_s_barrier();
    DSA2(1, 0, aA);
    asm volatile("s_waitcnt lgkmcnt(4)" ::: "memory");
    __builtin_amdgcn_sched_barrier(0);
    MMA(3, aB);
    __builtin_amdgcn_s_barrier();
    // ph5: b(buf1) + next-a(mc1); MMA mc0
    DSB8(1); DSA2(1, 1, aB); STAGE(0, 0, 0, t2);
    PH_TAIL(0, aA)
    // ph6
    DSA2(1, 2, aA); STAGE(0, 1, 0, t2);
    PH_TAIL(1, aB)
    // ph7
    DSA2(1, 3, aB); STAGE(1, 0, 1, t3);
    PH_TAIL(2, aA)
    // ph8: vmcnt + collective barrier BEFORE cross-buffer a-read
    STAGE(1, 1, 1, t3);
    asm volatile("s_waitcnt vmcnt(4)" ::: "memory");  // buf0 (tile t2) landed
    __builtin_amdgcn_s_barrier();
    DSA2(0, 0, aA);
    asm volatile("s_waitcnt lgkmcnt(4)" ::: "memory");
    __builtin_amdgcn_sched_barrier(0);
    MMA(3, aB);
    __builtin_amdgcn_s_barrier();
  }
#undef PH_TAIL

  // drain our asm ds_reads before leaving the asm-managed domain
  asm volatile("s_waitcnt lgkmcnt(0)" ::: "memory");

  // ---- epilogue: fused gate split ----
#pragma unroll
  for (int mi = 0; mi < 8; mi++) {
#pragma unroll
    for (int ni = 0; ni < 4; ni++) {
      const int ncol = n0 + wn * 64 + ni * 16 + fr;
      const int gate = ncol >> 9, j = ncol & 511;
#pragma unroll
      for (int jj = 0; jj < 4; jj++) {
        const size_t rb = (size_t)(m0 + wm * 128 + mi * 16 + fq * 4 + jj);
        const float v = acc[mi][ni][jj];
        if (gate == 0)      U2[rb * 1024 + j]       = f2bf(sigm(v) * Sv[rb * 512 + j]);
        else if (gate == 1) U2[rb * 1024 + 512 + j] = f2bf(sigm(v) * Av[rb * 512 + j]);
        else if (gate == 2) Zp[rb * 512 + j]  = f2bf(v);
        else                XHp[rb * 512 + j] = f2bf(v);
      }
    }
  }
}

// ---- GEMM2: m97 128x128 structure, fused final epilogue -------------------
__global__ __launch_bounds__(256) void gemm_bt2(
    const unsigned short* __restrict__ Amat,
    const unsigned short* __restrict__ Bmat,
    const int K,
    const float* __restrict__ Sv,
    const unsigned short* __restrict__ Zp,
    const unsigned short* __restrict__ XHp, float* __restrict__ Out)
{
  constexpr int BK = 32;
  __shared__ __align__(16) unsigned short sA[128 * BK];
  __shared__ __align__(16) unsigned short sB[128 * BK];

  const int tid  = threadIdx.x;
  const int lane = tid & 63;
  const int wave = tid >> 6;
  const int wr = wave >> 1, wc = wave & 1;
  const int m0 = blockIdx.y * 128, n0 = blockIdx.x * 128;
  const int q = tid >> 2, r = tid & 3;

  const unsigned short* gA = Amat + (size_t)(m0 + q) * K + r * 8;
  const unsigned short* gB = Bmat + (size_t)(n0 + q) * K + r * 8;

  f32x4 acc[4][4] = {};
  const int fr = lane & 15, fq = lane >> 4;

  for (int kt = 0; kt < K; kt += BK) {
    gload_lds16(gA + kt,                  &sA[tid * 8]);
    gload_lds16(gA + kt + (size_t)64 * K, &sA[2048 + tid * 8]);
    gload_lds16(gB + kt,                  &sB[tid * 8]);
    gload_lds16(gB + kt + (size_t)64 * K, &sB[2048 + tid * 8]);
    __syncthreads();

    short8 a[4], b[4];
#pragma unroll
    for (int mt = 0; mt < 4; mt++)
      a[mt] = *(const short8*)&sA[(wr * 64 + mt * 16 + fr) * 32 + fq * 8];
#pragma unroll
    for (int nt = 0; nt < 4; nt++)
      b[nt] = *(const short8*)&sB[(wc * 64 + nt * 16 + fr) * 32 + fq * 8];
#pragma unroll
    for (int mt = 0; mt < 4; mt++)
#pragma unroll
      for (int nt = 0; nt < 4; nt++)
        acc[mt][nt] = __builtin_amdgcn_mfma_f32_16x16x32_bf16(a[mt], b[nt], acc[mt][nt], 0, 0, 0);
    __syncthreads();
  }

#pragma unroll
  for (int mt = 0; mt < 4; mt++) {
#pragma unroll
    for (int nt = 0; nt < 4; nt++) {
      const int ncol = n0 + wc * 64 + nt * 16 + fr;
#pragma unroll
      for (int jj = 0; jj < 4; jj++) {
        const size_t rb = (size_t)(m0 + wr * 64 + mt * 16 + fq * 4 + jj);
        const size_t o = rb * 512 + ncol;
        const float z = sigm(bf2f(Zp[o]));
        const float h = tanh_fast(bf2f(XHp[o]) + acc[mt][nt][jj]);
        Out[o] = (1.0f - z) * Sv[o] + z * h;
      }
    }
  }
}

// ---------------------------------------------------------------------------

extern "C" void kernel_launch(void* const* d_in, const int* in_sizes, int n_in,
                              void* d_out, int out_size, void* d_ws, size_t ws_size,
                              hipStream_t stream) {
  const float* X   = (const float*)d_in[0];
  const float* S   = (const float*)d_in[1];
  const float* A   = (const float*)d_in[2];
  const float* Wxr = (const float*)d_in[3];
  const float* Wxp = (const float*)d_in[4];
  const float* Wxz = (const float*)d_in[5];
  const float* Wxh = (const float*)d_in[6];
  const float* Whr = (const float*)d_in[7];
  const float* Whp = (const float*)d_in[8];
  const float* Whz = (const float*)d_in[9];
  const float* Whh = (const float*)d_in[10];
  const float* Vhr = (const float*)d_in[11];
  const float* Vhp = (const float*)d_in[12];
  const float* Vhz = (const float*)d_in[13];
  const float* Vhh = (const float*)d_in[14];

  char* ws = (char*)d_ws;
  size_t off = 0;
  auto alloc = [&](size_t bytes) -> void* {
    void* p = ws + off;
    off += (bytes + 255) & ~(size_t)255;
    return p;
  };
  unsigned short* W1 = (unsigned short*)alloc((size_t)2048 * 2048 * 2);
  unsigned short* W2 = (unsigned short*)alloc((size_t)512 * 1024 * 2);
  unsigned short* U  = (unsigned short*)alloc((size_t)Bn * 2048 * 2);
  unsigned short* U2 = (unsigned short*)alloc((size_t)Bn * 1024 * 2);
  unsigned short* Zp = (unsigned short*)alloc((size_t)Bn * 512 * 2);
  unsigned short* XH = (unsigned short*)alloc((size_t)Bn * 512 * 2);

  pack_w1<<<2048, 256, 0, stream>>>(Wxr, Wxp, Wxz, Wxh, Whr, Whp, Whz, Vhr, Vhp, Vhz, W1);
  pack_w2<<<256, 256, 0, stream>>>(Whh, Vhh, W2);
  pack_u <<<Bn, 256, 0, stream>>>(X, S, A, U);

  (void)hipFuncSetAttribute((const void*)gemm256_epi1,
                            hipFuncAttributeMaxDynamicSharedMemorySize, 131072);

  // GEMM1: P = U(16384x2048) @ W1^T(2048x2048), fused gate epilogue
  gemm256_epi1<<<dim3(2048 / 256, Bn / 256), 512, 131072, stream>>>(
      U, W1, 2048, S, A, U2, Zp, XH);

  // GEMM2: U2(16384x1024) @ W2^T(512x1024), fused final epilogue -> d_out
  gemm_bt2<<<dim3(512 / 128, Bn / 128), 256, 0, stream>>>(
      U2, W2, 1024, S, Zp, XH, (float*)d_out);
}

// Round 5
// 361.372 us; speedup vs baseline: 1.3693x; 1.3693x over previous
//
#include <hip/hip_runtime.h>
#include <hip/hip_bf16.h>
#include <stdint.h>

// ---------------------------------------------------------------------------
// UpdateSpeaker: GRU-like gating block.
//   r,p,z = sigmoid(X@Wx*^T + S@Wh*^T + A@Vh*^T)
//   h~    = tanh(X@Wxh^T + (r*S)@Whh^T + (p*A)@Vhh^T)
//   out   = (1-z)*S + z*h~
// GEMM1: SIMPLE 2-phase 256x256 BK=64 double-buffer (T3 minimum form):
//        stage(next buf) -> compute(cur) -> one __syncthreads per K-tile.
//        + XCD swizzle: n-panel per XCD (W1 panel pinned in XCD L2).
// GEMM2: m97 128x128 structure.
// ---------------------------------------------------------------------------

typedef short  short8  __attribute__((ext_vector_type(8)));
typedef unsigned short ushort8 __attribute__((ext_vector_type(8)));
typedef float  f32x4   __attribute__((ext_vector_type(4)));

static constexpr int Bn  = 16384;  // batch

__device__ __forceinline__ unsigned short f2bf(float x) {
  union { float f; unsigned u; } v; v.f = x;
  unsigned r = v.u + 0x7fffu + ((v.u >> 16) & 1u);   // RNE
  return (unsigned short)(r >> 16);
}
__device__ __forceinline__ float bf2f(unsigned short h) {
  union { unsigned u; float f; } v; v.u = ((unsigned)h) << 16; return v.f;
}
__device__ __forceinline__ float sigm(float x) { return 1.0f / (1.0f + __expf(-x)); }
__device__ __forceinline__ float tanh_fast(float x) {
  return 2.0f / (1.0f + __expf(-2.0f * x)) - 1.0f;
}

__device__ __forceinline__ void gload_lds16(const void* g, void* l) {
  __builtin_amdgcn_global_load_lds((const __attribute__((address_space(1))) void*)g,
                                   (__attribute__((address_space(3))) void*)l,
                                   16, 0, 0);
}

// ---- weight packing -------------------------------------------------------
__global__ __launch_bounds__(256) void pack_w1(
    const float* __restrict__ xr, const float* __restrict__ xp,
    const float* __restrict__ xz, const float* __restrict__ xh,
    const float* __restrict__ hr, const float* __restrict__ hp, const float* __restrict__ hz,
    const float* __restrict__ vr, const float* __restrict__ vp, const float* __restrict__ vz,
    unsigned short* __restrict__ W1)
{
  int idx = blockIdx.x * 256 + threadIdx.x;
  int n  = idx >> 8;
  int k8 = (idx & 255) << 3;
  int g = n >> 9, j = n & 511;
  const float* src = nullptr;
  if (k8 < 1024) {
    const float* x = (g == 0) ? xr : (g == 1) ? xp : (g == 2) ? xz : xh;
    src = x + (size_t)j * 1024 + k8;
  } else if (k8 < 1536) {
    if (g < 3) { const float* h = (g == 0) ? hr : (g == 1) ? hp : hz; src = h + (size_t)j * 512 + (k8 - 1024); }
  } else {
    if (g < 3) { const float* v = (g == 0) ? vr : (g == 1) ? vp : vz; src = v + (size_t)j * 512 + (k8 - 1536); }
  }
  ushort8 o;
  if (src) { for (int i = 0; i < 8; i++) o[i] = f2bf(src[i]); }
  else     { for (int i = 0; i < 8; i++) o[i] = 0; }
  *(ushort8*)&W1[(size_t)n * 2048 + k8] = o;
}

__global__ __launch_bounds__(256) void pack_w2(
    const float* __restrict__ hh, const float* __restrict__ vh,
    unsigned short* __restrict__ W2)
{
  int idx = blockIdx.x * 256 + threadIdx.x;
  int n  = idx >> 7;
  int k8 = (idx & 127) << 3;
  const float* src = (k8 < 512) ? hh + (size_t)n * 512 + k8
                                : vh + (size_t)n * 512 + (k8 - 512);
  ushort8 o;
  for (int i = 0; i < 8; i++) o[i] = f2bf(src[i]);
  *(ushort8*)&W2[(size_t)n * 1024 + k8] = o;
}

__global__ __launch_bounds__(256) void pack_u(
    const float* __restrict__ X, const float* __restrict__ S, const float* __restrict__ A,
    unsigned short* __restrict__ U)
{
  int idx = blockIdx.x * 256 + threadIdx.x;
  int b  = idx >> 8;
  int c8 = (idx & 255) << 3;
  const float* src = (c8 < 1024) ? X + (size_t)b * 1024 + c8
                   : (c8 < 1536) ? S + (size_t)b * 512 + (c8 - 1024)
                                 : A + (size_t)b * 512 + (c8 - 1536);
  f32x4 lo = *(const f32x4*)src;
  f32x4 hi = *(const f32x4*)(src + 4);
  ushort8 o;
  o[0] = f2bf(lo[0]); o[1] = f2bf(lo[1]); o[2] = f2bf(lo[2]); o[3] = f2bf(lo[3]);
  o[4] = f2bf(hi[0]); o[5] = f2bf(hi[1]); o[6] = f2bf(hi[2]); o[7] = f2bf(hi[3]);
  *(ushort8*)&U[(size_t)b * 2048 + c8] = o;
}

// ---- GEMM1: 256x256, BK=64, 8 waves (2Mx4N), simple 2-phase dbuf ----------
// LDS per buffer (64 KiB): A tile 256x64 bf16 @ +0, B tile @ +32768.
// Swizzle (T2): LDS(row, slot16B) holds global (row, slot ^ (row&7)), via
// pre-swizzled global source (linear DMA dest) + XOR on ds_read.
__global__ __launch_bounds__(512, 1) void gemm256_epi1(
    const unsigned short* __restrict__ Amat,
    const unsigned short* __restrict__ Bmat,
    const int K,
    const float* __restrict__ Sv, const float* __restrict__ Av,
    unsigned short* __restrict__ U2, unsigned short* __restrict__ Zp,
    unsigned short* __restrict__ XHp)
{
  extern __shared__ char lds[];

  const int tid  = threadIdx.x;
  const int lane = tid & 63, wave = tid >> 6;
  const int wm = wave >> 2, wn = wave & 3;      // 2 x 4 wave grid
  const int fr = lane & 15, fq = lane >> 4;
  // XCD swizzle: bid%8 = n-panel (one per XCD -> W1 panel L2-pinned)
  const int n0 = (blockIdx.x & 7) * 256;
  const int m0 = (blockIdx.x >> 3) * 256;

  // staging: thread t covers rows (t>>3)+j*64, 16B-slot (t&7), j=0..3
  const int srow  = tid >> 3;
  const int sslot = (tid & 7) ^ (srow & 7);     // pre-swizzled source slot
  const unsigned short* gA = Amat + (size_t)(m0 + srow) * K + sslot * 8;
  const unsigned short* gB = Bmat + (size_t)(n0 + srow) * K + sslot * 8;
  const size_t K64 = (size_t)64 * K;

  // ds_read swizzle offsets
  int swz[2];
  swz[0] = ((fq    ) ^ (fr & 7)) << 4;
  swz[1] = ((fq + 4) ^ (fr & 7)) << 4;
  const int aoff = wm * 16384 + fr * 128;            // + mi*2048 + swz
  const int boff = 32768 + wn * 8192 + fr * 128;     // + ni*2048 + swz

  f32x4 acc[8][4] = {};

  const int NT = K >> 6;   // K-tiles of 64

  auto STAGE = [&](int buf, int tile) {   // 8 gload_lds16 per thread
    const int bufo = buf << 16;
#pragma unroll
    for (int j = 0; j < 4; j++) {
      gload_lds16(gA + (size_t)j * K64 + (tile << 6), lds + bufo + tid * 16 + j * 8192);
      gload_lds16(gB + (size_t)j * K64 + (tile << 6), lds + bufo + 32768 + tid * 16 + j * 8192);
    }
  };
  auto COMPUTE = [&](int buf) {
    const int bufo = buf << 16;
    short8 b[4][2];
#pragma unroll
    for (int ni = 0; ni < 4; ni++)
#pragma unroll
      for (int ks = 0; ks < 2; ks++)
        b[ni][ks] = *(const short8*)(lds + bufo + boff + ni * 2048 + swz[ks]);
#pragma unroll
    for (int c = 0; c < 4; c++) {        // mi-chunks of 2 rows
      short8 a[2][2];
#pragma unroll
      for (int i = 0; i < 2; i++)
#pragma unroll
        for (int ks = 0; ks < 2; ks++)
          a[i][ks] = *(const short8*)(lds + bufo + aoff + (c * 2 + i) * 2048 + swz[ks]);
#pragma unroll
      for (int i = 0; i < 2; i++)
#pragma unroll
        for (int ni = 0; ni < 4; ni++)
#pragma unroll
          for (int ks = 0; ks < 2; ks++)
            acc[c * 2 + i][ni] = __builtin_amdgcn_mfma_f32_16x16x32_bf16(
                a[i][ks], b[ni][ks], acc[c * 2 + i][ni], 0, 0, 0);
    }
  };

  // prologue
  STAGE(0, 0);
  __syncthreads();                       // drains tile0 DMA

  int cur = 0;
  for (int t = 0; t < NT - 1; ++t) {
    STAGE(cur ^ 1, t + 1);               // issue next tile BEFORE compute
    COMPUTE(cur);                        // ~2500 cyc of MFMA covers load latency
    __syncthreads();                     // vmcnt(0)+lgkmcnt(0)+barrier: next buf ready,
    cur ^= 1;                            // cur buf fully consumed
  }
  COMPUTE(cur);

  // ---- epilogue: fused gate split ----
#pragma unroll
  for (int mi = 0; mi < 8; mi++) {
#pragma unroll
    for (int ni = 0; ni < 4; ni++) {
      const int ncol = n0 + wn * 64 + ni * 16 + fr;
      const int gate = ncol >> 9, j = ncol & 511;
#pragma unroll
      for (int jj = 0; jj < 4; jj++) {
        const size_t rb = (size_t)(m0 + wm * 128 + mi * 16 + fq * 4 + jj);
        const float v = acc[mi][ni][jj];
        if (gate == 0)      U2[rb * 1024 + j]       = f2bf(sigm(v) * Sv[rb * 512 + j]);
        else if (gate == 1) U2[rb * 1024 + 512 + j] = f2bf(sigm(v) * Av[rb * 512 + j]);
        else if (gate == 2) Zp[rb * 512 + j]  = f2bf(v);
        else                XHp[rb * 512 + j] = f2bf(v);
      }
    }
  }
}

// ---- GEMM2: m97 128x128 structure, fused final epilogue -------------------
__global__ __launch_bounds__(256) void gemm_bt2(
    const unsigned short* __restrict__ Amat,
    const unsigned short* __restrict__ Bmat,
    const int K,
    const float* __restrict__ Sv,
    const unsigned short* __restrict__ Zp,
    const unsigned short* __restrict__ XHp, float* __restrict__ Out)
{
  constexpr int BK = 32;
  __shared__ __align__(16) unsigned short sA[128 * BK];
  __shared__ __align__(16) unsigned short sB[128 * BK];

  const int tid  = threadIdx.x;
  const int lane = tid & 63;
  const int wave = tid >> 6;
  const int wr = wave >> 1, wc = wave & 1;
  const int m0 = blockIdx.y * 128, n0 = blockIdx.x * 128;
  const int q = tid >> 2, r = tid & 3;

  const unsigned short* gA = Amat + (size_t)(m0 + q) * K + r * 8;
  const unsigned short* gB = Bmat + (size_t)(n0 + q) * K + r * 8;

  f32x4 acc[4][4] = {};
  const int fr = lane & 15, fq = lane >> 4;

  for (int kt = 0; kt < K; kt += BK) {
    gload_lds16(gA + kt,                  &sA[tid * 8]);
    gload_lds16(gA + kt + (size_t)64 * K, &sA[2048 + tid * 8]);
    gload_lds16(gB + kt,                  &sB[tid * 8]);
    gload_lds16(gB + kt + (size_t)64 * K, &sB[2048 + tid * 8]);
    __syncthreads();

    short8 a[4], b[4];
#pragma unroll
    for (int mt = 0; mt < 4; mt++)
      a[mt] = *(const short8*)&sA[(wr * 64 + mt * 16 + fr) * 32 + fq * 8];
#pragma unroll
    for (int nt = 0; nt < 4; nt++)
      b[nt] = *(const short8*)&sB[(wc * 64 + nt * 16 + fr) * 32 + fq * 8];
#pragma unroll
    for (int mt = 0; mt < 4; mt++)
#pragma unroll
      for (int nt = 0; nt < 4; nt++)
        acc[mt][nt] = __builtin_amdgcn_mfma_f32_16x16x32_bf16(a[mt], b[nt], acc[mt][nt], 0, 0, 0);
    __syncthreads();
  }

#pragma unroll
  for (int mt = 0; mt < 4; mt++) {
#pragma unroll
    for (int nt = 0; nt < 4; nt++) {
      const int ncol = n0 + wc * 64 + nt * 16 + fr;
#pragma unroll
      for (int jj = 0; jj < 4; jj++) {
        const size_t rb = (size_t)(m0 + wr * 64 + mt * 16 + fq * 4 + jj);
        const size_t o = rb * 512 + ncol;
        const float z = sigm(bf2f(Zp[o]));
        const float h = tanh_fast(bf2f(XHp[o]) + acc[mt][nt][jj]);
        Out[o] = (1.0f - z) * Sv[o] + z * h;
      }
    }
  }
}

// ---------------------------------------------------------------------------

extern "C" void kernel_launch(void* const* d_in, const int* in_sizes, int n_in,
                              void* d_out, int out_size, void* d_ws, size_t ws_size,
                              hipStream_t stream) {
  const float* X   = (const float*)d_in[0];
  const float* S   = (const float*)d_in[1];
  const float* A   = (const float*)d_in[2];
  const float* Wxr = (const float*)d_in[3];
  const float* Wxp = (const float*)d_in[4];
  const float* Wxz = (const float*)d_in[5];
  const float* Wxh = (const float*)d_in[6];
  const float* Whr = (const float*)d_in[7];
  const float* Whp = (const float*)d_in[8];
  const float* Whz = (const float*)d_in[9];
  const float* Whh = (const float*)d_in[10];
  const float* Vhr = (const float*)d_in[11];
  const float* Vhp = (const float*)d_in[12];
  const float* Vhz = (const float*)d_in[13];
  const float* Vhh = (const float*)d_in[14];

  char* ws = (char*)d_ws;
  size_t off = 0;
  auto alloc = [&](size_t bytes) -> void* {
    void* p = ws + off;
    off += (bytes + 255) & ~(size_t)255;
    return p;
  };
  unsigned short* W1 = (unsigned short*)alloc((size_t)2048 * 2048 * 2);
  unsigned short* W2 = (unsigned short*)alloc((size_t)512 * 1024 * 2);
  unsigned short* U  = (unsigned short*)alloc((size_t)Bn * 2048 * 2);
  unsigned short* U2 = (unsigned short*)alloc((size_t)Bn * 1024 * 2);
  unsigned short* Zp = (unsigned short*)alloc((size_t)Bn * 512 * 2);
  unsigned short* XH = (unsigned short*)alloc((size_t)Bn * 512 * 2);

  pack_w1<<<2048, 256, 0, stream>>>(Wxr, Wxp, Wxz, Wxh, Whr, Whp, Whz, Vhr, Vhp, Vhz, W1);
  pack_w2<<<256, 256, 0, stream>>>(Whh, Vhh, W2);
  pack_u <<<Bn, 256, 0, stream>>>(X, S, A, U);

  (void)hipFuncSetAttribute((const void*)gemm256_epi1,
                            hipFuncAttributeMaxDynamicSharedMemorySize, 131072);

  // GEMM1: P = U(16384x2048) @ W1^T(2048x2048), fused gate epilogue
  gemm256_epi1<<<512, 512, 131072, stream>>>(U, W1, 2048, S, A, U2, Zp, XH);

  // GEMM2: U2(16384x1024) @ W2^T(512x1024), fused final epilogue -> d_out
  gemm_bt2<<<dim3(512 / 128, Bn / 128), 256, 0, stream>>>(
      U2, W2, 1024, S, Zp, XH, (float*)d_out);
}